// Round 1
// baseline (319.522 us; speedup 1.0000x reference)
//
#include <hip/hip_runtime.h>

// ChebyKANLayer: y[t,o] = sum_{i,d} T_d(tanh(x[t,i])) * C[i,o,d]
//   = bias[o] + bf16-GEMM( A[t, k=(d-1)*1024+i] = T_d(tanh x), Bt[o][k] )
// T_d generated in-register via Chebyshev recurrence (no arccos/cos).

typedef __bf16 bf16;
typedef __bf16 bf16x8 __attribute__((ext_vector_type(8)));
typedef __bf16 bf16x2 __attribute__((ext_vector_type(2)));
typedef float f32x4 __attribute__((ext_vector_type(4)));

#define TOKENS 8192
#define IDIM   1024
#define ODIM   1024
#define KDIM   8192   // degrees 1..8, k = (d-1)*1024 + i

__device__ __forceinline__ void g2lds16(const void* g, void* l) {
  // each lane: 16B from its own global addr -> (wave-uniform lds base) + lane*16
  __builtin_amdgcn_global_load_lds(
      (const __attribute__((address_space(1))) unsigned int*)g,
      (__attribute__((address_space(3))) unsigned int*)l, 16, 0, 0);
}

// ---------------- prep 1: Bt[o][ (d-1)*1024 + i ] = bf16(C[i][o][d]), d=1..8 ----------------
__global__ __launch_bounds__(256)
void cheby_prep_bt(const float* __restrict__ C, bf16* __restrict__ Bt) {
  __shared__ float tile[32][289];               // +1 pad: 289%32==1 -> conflict-free strided reads
  const int i0 = blockIdx.x * 32, o0 = blockIdx.y * 32;
  const int tid = threadIdx.x;
  // read: for each local i, floats C[(i0+i)*9216 + o0*9 + c], c in [0,288) -- fully coalesced
  for (int idx = tid; idx < 32 * 288; idx += 256) {
    int i = idx / 288;
    int c = idx - i * 288;
    tile[i][c] = C[(size_t)(i0 + i) * 9216 + (size_t)o0 * 9 + c];
  }
  __syncthreads();
  // write: (o, d1, i-pair) with i fastest -> coalesced bf16x2 stores
  for (int idx = tid; idx < 4096; idx += 256) {
    int o  = idx >> 7;
    int r  = idx & 127;
    int d1 = r >> 4;            // 0..7  (degree d = d1+1)
    int ip = (r & 15) * 2;      // even i
    bf16x2 v;
    v.x = (bf16)tile[ip][o * 9 + d1 + 1];
    v.y = (bf16)tile[ip + 1][o * 9 + d1 + 1];
    *(bf16x2*)&Bt[(size_t)(o0 + o) * KDIM + d1 * 1024 + i0 + ip] = v;
  }
}

// ---------------- prep 2: bias[o] = sum_i C[i][o][0]  (the T_0 == 1 slab) ----------------
__global__ __launch_bounds__(256)
void cheby_prep_bias(const float* __restrict__ C, float* __restrict__ bias) {
  const int o = blockIdx.x;
  float s = 0.f;
  for (int i = threadIdx.x; i < IDIM; i += 256)
    s += C[((size_t)i * 1024 + o) * 9];
  #pragma unroll
  for (int off = 32; off > 0; off >>= 1) s += __shfl_down(s, off, 64);
  __shared__ float ps[4];
  if ((threadIdx.x & 63) == 0) ps[threadIdx.x >> 6] = s;
  __syncthreads();
  if (threadIdx.x == 0) bias[o] = ps[0] + ps[1] + ps[2] + ps[3];
}

// ---------------- fused basis-gen + bf16 GEMM ----------------
// 128x128 C-tile per block, 512 threads = 8 waves in 2x4 grid (wave tile 64m x 32n).
// K-loop: it (i-tile of 32) outer, d (1..8) inner; per slab BK=32:
//   A slab = T_d(tanh x) written from registers (recurrence), B slab via global_load_lds.
template <bool USE_WS>
__global__ __launch_bounds__(512, 4)
void cheby_gemm(const float* __restrict__ x, const float* __restrict__ C,
                const bf16* __restrict__ Bt, const float* __restrict__ bias,
                float* __restrict__ out) {
  __shared__ bf16 As[128 * 32];   // [t_local][k_local]
  __shared__ bf16 Bs[128 * 32];   // [o_local][k_local]

  const int tid  = threadIdx.x;
  const int lane = tid & 63, w = tid >> 6;
  const int wm = w >> 2, wn = w & 3;          // wave grid 2 x 4
  const int mb = blockIdx.x >> 3, nb = blockIdx.x & 7;  // n fastest -> n-col per XCD (L2 reuse of Bt)
  const int t0 = mb * 128, o0 = nb * 128;
  const int row = tid >> 2, q = tid & 3;      // A-gen: thread owns (row, i = q*8 .. q*8+7)

  const float* xp = x + (size_t)(t0 + row) * IDIM + q * 8;

  f32x4 acc[4][2];
  #pragma unroll
  for (int a = 0; a < 4; ++a)
    #pragma unroll
    for (int b = 0; b < 2; ++b) acc[a][b] = (f32x4){0.f, 0.f, 0.f, 0.f};

  f32x4 xv0 = *(const f32x4*)(xp);
  f32x4 xv1 = *(const f32x4*)(xp + 4);

  const int d0 = USE_WS ? 1 : 0;

  #pragma unroll 1
  for (int it = 0; it < 32; ++it) {
    // tanh once per (t,i); Chebyshev state in regs
    float t2[8], cur[8], prev[8];
    {
      float xs[8] = {xv0.x, xv0.y, xv0.z, xv0.w, xv1.x, xv1.y, xv1.z, xv1.w};
      #pragma unroll
      for (int j = 0; j < 8; ++j) {
        float e  = __expf(xs[j] + xs[j]);
        float th = 1.f - 2.f / (e + 1.f);          // tanh; saturates to +-1, NaN-free
        t2[j] = th + th;
        if (USE_WS) { cur[j] = th;  prev[j] = 1.f; }   // start at T_1 (T_0 folded into bias)
        else        { cur[j] = 1.f; prev[j] = th;  }   // start at T_0; T_{-1}=T_1=t trick
      }
    }

    for (int d = d0; d <= 8; ++d) {
      __syncthreads();                                  // prev MFMA done with As/Bs
      // ---- A slab: 8 bf16 per thread, one ds_write_b128 ----
      bf16x8 pk;
      #pragma unroll
      for (int j = 0; j < 8; ++j) pk[j] = (bf16)cur[j];
      *(bf16x8*)&As[row * 32 + q * 8] = pk;
      // ---- B slab ----
      if (USE_WS) {
        const int kbase = (d - 1) * 1024 + it * 32;
        const bf16* g = Bt + (size_t)(o0 + w * 16 + (lane >> 2)) * KDIM + kbase + (lane & 3) * 8;
        g2lds16(g, &Bs[w * 512]);                       // 1 instr/wave, 1KB each, 8 waves = 8KB
      } else {
        for (int idx = tid; idx < 4096; idx += 512) {
          int o = idx >> 5, ki = idx & 31;
          Bs[o * 32 + ki] = (bf16)C[((size_t)(it * 32 + ki) * 1024 + o0 + o) * 9 + d];
        }
      }
      if (d == d0 && it < 31) {                         // prefetch next x tile into regs
        xv0 = *(const f32x4*)(xp + (it + 1) * 32);
        xv1 = *(const f32x4*)(xp + (it + 1) * 32 + 4);
      }
      __syncthreads();                                  // staging complete (vmcnt+lgkm drained)
      // ---- MFMA: 4 m-tiles x 2 n-tiles of 16x16x32 ----
      bf16x8 af[4], bfr[2];
      #pragma unroll
      for (int mt = 0; mt < 4; ++mt)
        af[mt] = *(const bf16x8*)&As[(wm * 64 + mt * 16 + (lane & 15)) * 32 + (lane >> 4) * 8];
      #pragma unroll
      for (int nt = 0; nt < 2; ++nt)
        bfr[nt] = *(const bf16x8*)&Bs[(wn * 32 + nt * 16 + (lane & 15)) * 32 + (lane >> 4) * 8];
      #pragma unroll
      for (int mt = 0; mt < 4; ++mt)
        #pragma unroll
        for (int nt = 0; nt < 2; ++nt)
          acc[mt][nt] = __builtin_amdgcn_mfma_f32_16x16x32_bf16(af[mt], bfr[nt], acc[mt][nt], 0, 0, 0);
      // ---- recurrence: T_{d+1} = 2t*T_d - T_{d-1} ----
      #pragma unroll
      for (int j = 0; j < 8; ++j) {
        float nx = __builtin_fmaf(t2[j], cur[j], -prev[j]);
        prev[j] = cur[j];
        cur[j] = nx;
      }
    }
  }

  // ---- epilogue: C/D layout col=lane&15, row=quad*4+reg (m89/m91-verified) ----
  const int ln = lane & 15, quad = lane >> 4;
  const int obase = o0 + wn * 32 + ln;
  const size_t rbase = (size_t)(t0 + wm * 64 + quad * 4) * ODIM;
  float bv[2] = {0.f, 0.f};
  if (USE_WS) { bv[0] = bias[obase]; bv[1] = bias[obase + 16]; }
  #pragma unroll
  for (int mt = 0; mt < 4; ++mt)
    #pragma unroll
    for (int nt = 0; nt < 2; ++nt)
      #pragma unroll
      for (int r = 0; r < 4; ++r)
        out[rbase + (size_t)(mt * 16 + r) * ODIM + obase + nt * 16] = acc[mt][nt][r] + bv[nt];
}

extern "C" void kernel_launch(void* const* d_in, const int* in_sizes, int n_in,
                              void* d_out, int out_size, void* d_ws, size_t ws_size,
                              hipStream_t stream) {
  (void)in_sizes; (void)n_in; (void)out_size;
  const float* x = (const float*)d_in[0];
  const float* C = (const float*)d_in[1];
  float* out = (float*)d_out;

  const size_t bt_bytes = (size_t)ODIM * KDIM * sizeof(bf16);   // 16.78 MB
  const size_t need = bt_bytes + 1024 * sizeof(float);

  if (ws_size >= need) {
    bf16*  Bt   = (bf16*)d_ws;
    float* bias = (float*)((char*)d_ws + bt_bytes);
    cheby_prep_bt  <<<dim3(32, 32), 256, 0, stream>>>(C, Bt);
    cheby_prep_bias<<<1024, 256, 0, stream>>>(C, bias);
    cheby_gemm<true><<<512, 512, 0, stream>>>(x, C, Bt, bias, out);
  } else {
    // ws too small: same GEMM, B staged directly from coeffs (strided, L3-cached), d=0..8
    cheby_gemm<false><<<512, 512, 0, stream>>>(x, C, nullptr, nullptr, out);
  }
}

// Round 2
// 282.266 us; speedup vs baseline: 1.1320x; 1.1320x over previous
//
#include <hip/hip_runtime.h>

// ChebyKANLayer: y[t,o] = bias[o] + bf16-GEMM( A[t,k]=T_d(tanh x), Bt_sw[o][k] )
// K = 8192 (degrees 1..8; T_0 slab folded into bias). K traversal: i-tile (32) outer,
// degree-pair inner -> BK=64 stages. LDS XOR-swizzled (chunk^row&7); Bt pre-swizzled
// in ws so global_load_lds's contiguous write lands swizzled.

typedef __bf16 bf16;
typedef __bf16 bf16x8 __attribute__((ext_vector_type(8)));
typedef float f32x4 __attribute__((ext_vector_type(4)));

#define KSTAGES 128   // 32 i-tiles x 4 degree-pairs, BK=64

__device__ __forceinline__ void g2lds16(const void* g, void* l) {
  __builtin_amdgcn_global_load_lds(
      (const __attribute__((address_space(1))) unsigned int*)g,
      (__attribute__((address_space(3))) unsigned int*)l, 16, 0, 0);
}

// ---- prep: Bt_sw[(o*128 + it*4+p)*64 + c'*8 + e] = bf16(C[it*32+(c&3)*8+e][o][2p+1+(c>>2)])
//      with c = c' ^ (o&7); plus bias[o] += sum_i C[i][o][0]  (atomic, bias pre-zeroed)
__global__ __launch_bounds__(256)
void cheby_prep(const float* __restrict__ C, bf16* __restrict__ Bt,
                float* __restrict__ bias) {
  __shared__ float tile[32][289];                    // [i_local][o_local*9 + d], pad->289
  const int it = blockIdx.x, i0 = it * 32, o0 = blockIdx.y * 32;
  const int tid = threadIdx.x;
  for (int idx = tid; idx < 32 * 288; idx += 256) {  // coalesced read of C block
    int i = idx / 288, c = idx - i * 288;
    tile[i][c] = C[(size_t)(i0 + i) * 9216 + (size_t)o0 * 9 + c];
  }
  __syncthreads();
  for (int idx = tid; idx < 1024; idx += 256) {      // 32 o x 4 p x 8 c' -> bf16x8 stores
    int o  = idx >> 5;
    int p  = (idx >> 3) & 3;
    int cp = idx & 7;
    int og = o0 + o;
    int c  = cp ^ (og & 7);
    int d  = 2 * p + 1 + (c >> 2);
    int ib = (c & 3) * 8;
    bf16x8 v;
    #pragma unroll
    for (int e = 0; e < 8; ++e) v[e] = (bf16)tile[ib + e][o * 9 + d];
    *(bf16x8*)&Bt[((size_t)og * KSTAGES + it * 4 + p) * 64 + cp * 8] = v;
  }
  if (tid < 32) {                                    // T_0 == 1 slab -> bias
    float s = 0.f;
    #pragma unroll
    for (int i = 0; i < 32; ++i) s += tile[i][tid * 9];
    atomicAdd(&bias[o0 + tid], s);
  }
}

// ---- fused basis-gen + GEMM: 128x128 tile, 512 thr = 8 waves (2x4), wave tile 64x32,
//      BK=64 (one i-tile of 32 x 2 degrees per stage), 256 stages -> 256 barrier-pairs halved.
__global__ __launch_bounds__(512, 4)
void cheby_gemm(const float* __restrict__ x, const bf16* __restrict__ Bt,
                const float* __restrict__ bias, float* __restrict__ out) {
  __shared__ bf16 As[128 * 64];
  __shared__ bf16 Bs[128 * 64];

  const int tid  = threadIdx.x;
  const int lane = tid & 63, w = tid >> 6;
  const int wm = w >> 2, wn = w & 3;
  const int mb = blockIdx.x >> 3, nb = blockIdx.x & 7;   // nb = XCD id -> Bt slice L2-resident
  const int t0 = mb * 128, o0 = nb * 128;

  // A-gen: thread owns token-row arow, i-chunk q (8 elems); emits 2 degree-chunks/stage
  const int arow = tid >> 2, q = tid & 3;
  const int aw0 = arow * 64 + ((q ^ (arow & 7)) * 8);          // swizzled chunk q   (deg 2p+1)
  const int aw1 = arow * 64 + (((q + 4) ^ (arow & 7)) * 8);    // swizzled chunk q+4 (deg 2p+2)
  const float* xp = x + (size_t)(t0 + arow) * 1024 + q * 8;

  // B staging: wave w owns rows [w*16, w*16+16), 2KB/stage -> two g2lds of 1KB
  const int brow = w * 16 + (lane >> 3);
  const size_t bg0 = (size_t)(o0 + brow) * (KSTAGES * 64) + (size_t)(lane & 7) * 8;
  const size_t bg1 = (size_t)(o0 + brow + 8) * (KSTAGES * 64) + (size_t)(lane & 7) * 8;
  bf16* bl0 = &Bs[w * 1024];
  bf16* bl1 = &Bs[w * 1024 + 512];

  const int ml = lane & 15, kc = lane >> 4;   // fragment row-low / 16B k-chunk

  f32x4 acc[4][2];
  #pragma unroll
  for (int a = 0; a < 4; ++a)
    #pragma unroll
    for (int b = 0; b < 2; ++b) acc[a][b] = (f32x4){0.f, 0.f, 0.f, 0.f};

  f32x4 xv0 = *(const f32x4*)(xp);
  f32x4 xv1 = *(const f32x4*)(xp + 4);

  #pragma unroll 1
  for (int it = 0; it < 32; ++it) {
    float t2[8], cur[8], prev[8];
    {
      float xs[8] = {xv0.x, xv0.y, xv0.z, xv0.w, xv1.x, xv1.y, xv1.z, xv1.w};
      #pragma unroll
      for (int j = 0; j < 8; ++j) {
        float e  = __expf(xs[j] + xs[j]);
        float th = 1.f - 2.f / (e + 1.f);        // tanh, saturating, NaN-free
        t2[j] = th + th;
        cur[j] = th; prev[j] = 1.f;              // start at T_1 (T_0 in bias)
      }
    }
    #pragma unroll 1
    for (int p = 0; p < 4; ++p) {
      __syncthreads();                            // prior MFMA done with As/Bs
      bf16x8 pk0, pk1;
      #pragma unroll
      for (int j = 0; j < 8; ++j) {
        pk0[j] = (bf16)cur[j];
        float nx = __builtin_fmaf(t2[j], cur[j], -prev[j]);
        prev[j] = cur[j]; cur[j] = nx;
      }
      #pragma unroll
      for (int j = 0; j < 8; ++j) {
        pk1[j] = (bf16)cur[j];
        float nx = __builtin_fmaf(t2[j], cur[j], -prev[j]);
        prev[j] = cur[j]; cur[j] = nx;
      }
      *(bf16x8*)&As[aw0] = pk0;
      *(bf16x8*)&As[aw1] = pk1;
      {
        const size_t soff = (size_t)(it * 4 + p) * 64;
        g2lds16(Bt + bg0 + soff, bl0);
        g2lds16(Bt + bg1 + soff, bl1);
      }
      if (p == 0 && it < 31) {                    // prefetch next x tile
        xv0 = *(const f32x4*)(xp + (it + 1) * 32);
        xv1 = *(const f32x4*)(xp + (it + 1) * 32 + 4);
      }
      __syncthreads();                            // staging drained (vmcnt+lgkm)
      #pragma unroll
      for (int ks = 0; ks < 2; ++ks) {
        const int cp = ((ks * 4 + kc) ^ (ml & 7)) * 8;   // swizzled 16B chunk, same for A & B
        bf16x8 af[4], bfr[2];
        #pragma unroll
        for (int mt = 0; mt < 4; ++mt)
          af[mt] = *(const bf16x8*)&As[(wm * 64 + mt * 16 + ml) * 64 + cp];
        #pragma unroll
        for (int nt = 0; nt < 2; ++nt)
          bfr[nt] = *(const bf16x8*)&Bs[(wn * 32 + nt * 16 + ml) * 64 + cp];
        #pragma unroll
        for (int mt = 0; mt < 4; ++mt)
          #pragma unroll
          for (int nt = 0; nt < 2; ++nt)
            acc[mt][nt] = __builtin_amdgcn_mfma_f32_16x16x32_bf16(af[mt], bfr[nt], acc[mt][nt], 0, 0, 0);
      }
    }
  }

  // epilogue: C/D layout col=lane&15, row=quad*4+reg (m89/m91)
  const int quad = lane >> 4;
  const int obase = o0 + wn * 32 + ml;
  const size_t rbase = (size_t)(t0 + wm * 64 + quad * 4) * 1024;
  float bv0 = bias[obase], bv1 = bias[obase + 16];
  #pragma unroll
  for (int mt = 0; mt < 4; ++mt)
    #pragma unroll
    for (int r = 0; r < 4; ++r) {
      out[rbase + (size_t)(mt * 16 + r) * 1024 + obase]      = acc[mt][0][r] + bv0;
      out[rbase + (size_t)(mt * 16 + r) * 1024 + obase + 16] = acc[mt][1][r] + bv1;
    }
}

// ---- fallback (ws too small) — correct, slow, should never run
__global__ __launch_bounds__(256)
void cheby_naive(const float* __restrict__ x, const float* __restrict__ C,
                 float* __restrict__ out) {
  const int t = blockIdx.x, tid = threadIdx.x;
  float acc[4] = {0.f, 0.f, 0.f, 0.f};
  for (int i = 0; i < 1024; ++i) {
    float th = tanhf(x[(size_t)t * 1024 + i]);
    float T[9]; T[0] = 1.f; T[1] = th;
    #pragma unroll
    for (int d = 2; d < 9; ++d) T[d] = 2.f * th * T[d - 1] - T[d - 2];
    #pragma unroll
    for (int j = 0; j < 4; ++j) {
      const float* cp = &C[((size_t)i * 1024 + tid + j * 256) * 9];
      float s = 0.f;
      #pragma unroll
      for (int d = 0; d < 9; ++d) s += T[d] * cp[d];
      acc[j] += s;
    }
  }
  #pragma unroll
  for (int j = 0; j < 4; ++j) out[(size_t)t * 1024 + tid + j * 256] = acc[j];
}

extern "C" void kernel_launch(void* const* d_in, const int* in_sizes, int n_in,
                              void* d_out, int out_size, void* d_ws, size_t ws_size,
                              hipStream_t stream) {
  (void)in_sizes; (void)n_in; (void)out_size;
  const float* x = (const float*)d_in[0];
  const float* C = (const float*)d_in[1];
  float* out = (float*)d_out;

  const size_t bt_bytes = (size_t)1024 * KSTAGES * 64 * sizeof(bf16);  // 16.78 MB
  if (ws_size >= bt_bytes + 1024 * sizeof(float)) {
    bf16*  Bt   = (bf16*)d_ws;
    float* bias = (float*)((char*)d_ws + bt_bytes);
    hipMemsetAsync(bias, 0, 1024 * sizeof(float), stream);
    cheby_prep<<<dim3(32, 32), 256, 0, stream>>>(C, Bt, bias);
    cheby_gemm<<<512, 512, 0, stream>>>(x, Bt, bias, out);
  } else {
    cheby_naive<<<8192, 256, 0, stream>>>(x, C, out);
  }
}

// Round 3
// 269.773 us; speedup vs baseline: 1.1844x; 1.0463x over previous
//
#include <hip/hip_runtime.h>

// ChebyKANLayer: y[t,o] = bias[o] + bf16-GEMM( A[t,k]=T_d(tanh x), Bt_sw[o][k] )
// K = 8192 (deg 1..8; T_0 folded into bias). R3: 128x256 tile, 1 block/CU,
// full LDS double-buffer, ONE barrier per BK=64 stage; g2lds for stage s+1
// issued before the MFMA phase of stage s (drain lands during MFMA).

typedef __bf16 bf16;
typedef __bf16 bf16x8 __attribute__((ext_vector_type(8)));
typedef float f32x4 __attribute__((ext_vector_type(4)));

#define KSTAGES 128   // 32 i-tiles x 4 degree-pairs, BK=64

__device__ __forceinline__ void g2lds16(const void* g, void* l) {
  __builtin_amdgcn_global_load_lds(
      (const __attribute__((address_space(1))) unsigned int*)g,
      (__attribute__((address_space(3))) unsigned int*)l, 16, 0, 0);
}

// ---- prep (unchanged from R2): Bt_sw[(o*128 + stage)*64 + c'*8 + e], c = c'^(o&7),
//      d = 2p+1+(c>>2), i = it*32+(c&3)*8+e ; bias[o] += sum_i C[i][o][0]
__global__ __launch_bounds__(256)
void cheby_prep(const float* __restrict__ C, bf16* __restrict__ Bt,
                float* __restrict__ bias) {
  __shared__ float tile[32][289];
  const int it = blockIdx.x, i0 = it * 32, o0 = blockIdx.y * 32;
  const int tid = threadIdx.x;
  for (int idx = tid; idx < 32 * 288; idx += 256) {
    int i = idx / 288, c = idx - i * 288;
    tile[i][c] = C[(size_t)(i0 + i) * 9216 + (size_t)o0 * 9 + c];
  }
  __syncthreads();
  for (int idx = tid; idx < 1024; idx += 256) {
    int o  = idx >> 5;
    int p  = (idx >> 3) & 3;
    int cp = idx & 7;
    int og = o0 + o;
    int c  = cp ^ (og & 7);
    int d  = 2 * p + 1 + (c >> 2);
    int ib = (c & 3) * 8;
    bf16x8 v;
    #pragma unroll
    for (int e = 0; e < 8; ++e) v[e] = (bf16)tile[ib + e][o * 9 + d];
    *(bf16x8*)&Bt[((size_t)og * KSTAGES + it * 4 + p) * 64 + cp * 8] = v;
  }
  if (tid < 32) {
    float s = 0.f;
    #pragma unroll
    for (int i = 0; i < 32; ++i) s += tile[i][tid * 9];
    atomicAdd(&bias[o0 + tid], s);
  }
}

// ---- fused basis-gen + GEMM: 128x256 tile, 512 thr = 8 waves (2m x 4n), wave 64x64.
__global__ __launch_bounds__(512, 2)
void cheby_gemm(const float* __restrict__ x, const bf16* __restrict__ Bt,
                const float* __restrict__ bias, float* __restrict__ out) {
  __shared__ bf16 As[2][128 * 64];   // 2 x 16 KB
  __shared__ bf16 Bs[2][256 * 64];   // 2 x 32 KB

  const int tid  = threadIdx.x;
  const int lane = tid & 63, w = tid >> 6;
  const int wm = w >> 2, wn = w & 3;                    // wave grid 2 x 4, tile 64x64
  const int nb = blockIdx.x & 3, mb = blockIdx.x >> 2;  // nb = bid&3: stable per XCD
  const int t0 = mb * 128, o0 = nb * 256;

  // A-gen: thread owns token-row arow, i-chunk q; emits 2 degree-chunks/stage
  const int arow = tid >> 2, q = tid & 3;
  const int aw0 = arow * 64 + ((q ^ (arow & 7)) * 8);
  const int aw1 = arow * 64 + (((q + 4) ^ (arow & 7)) * 8);
  const float* xp = x + (size_t)(t0 + arow) * 1024 + q * 8;

  // B staging: wave w owns o-rows [w*32, w*32+32): 4 g2lds of 1 KB each
  const size_t bg = (size_t)(o0 + w * 32 + (lane >> 3)) * (KSTAGES * 64) + (size_t)(lane & 7) * 8;

  const int ml = lane & 15, kc = lane >> 4, ml7 = lane & 7;

  f32x4 acc[4][4];
  #pragma unroll
  for (int a = 0; a < 4; ++a)
    #pragma unroll
    for (int b = 0; b < 4; ++b) acc[a][b] = (f32x4){0.f, 0.f, 0.f, 0.f};

  f32x4 xv0 = *(const f32x4*)(xp);
  f32x4 xv1 = *(const f32x4*)(xp + 4);
  float t2[8], cur[8], prev[8];

  // gen(k): produce stage k's A-slab into As[k&1], launch B g2lds into Bs[k&1]
  auto gen = [&](int k) {
    const int bi = k & 1;
    if ((k & 3) == 0) {                       // new i-tile: fresh tanh
      float xs[8] = {xv0.x, xv0.y, xv0.z, xv0.w, xv1.x, xv1.y, xv1.z, xv1.w};
      #pragma unroll
      for (int j = 0; j < 8; ++j) {
        float e  = __expf(xs[j] + xs[j]);
        float th = 1.f - 2.f / (e + 1.f);     // tanh, saturating, NaN-free
        t2[j] = th + th;
        cur[j] = th; prev[j] = 1.f;           // start at T_1 (T_0 in bias)
      }
      const int itn = (k >> 2) + 1;
      if (itn < 32) {                         // prefetch next x tile (used 4 stages later)
        xv0 = *(const f32x4*)(xp + itn * 32);
        xv1 = *(const f32x4*)(xp + itn * 32 + 4);
      }
    }
    bf16x8 pk0, pk1;
    #pragma unroll
    for (int j = 0; j < 8; ++j) {
      pk0[j] = (bf16)cur[j];
      float nx = __builtin_fmaf(t2[j], cur[j], -prev[j]);
      prev[j] = cur[j]; cur[j] = nx;
    }
    #pragma unroll
    for (int j = 0; j < 8; ++j) {
      pk1[j] = (bf16)cur[j];
      float nx = __builtin_fmaf(t2[j], cur[j], -prev[j]);
      prev[j] = cur[j]; cur[j] = nx;
    }
    *(bf16x8*)&As[bi][aw0] = pk0;
    *(bf16x8*)&As[bi][aw1] = pk1;
    const size_t soff = (size_t)k * 64;
    #pragma unroll
    for (int b = 0; b < 4; ++b)
      g2lds16(Bt + bg + (size_t)b * 8 * (KSTAGES * 64) + soff,
              &Bs[bi][(w * 32 + b * 8) * 64]);
  };

  gen(0);                                      // prologue: stage 0 into buf 0

  #pragma unroll 1
  for (int s = 0; s < KSTAGES; ++s) {
    const int bi = s & 1;
    __syncthreads();   // stage-s data ready in buf bi; all MFMA(s-1) reads of buf bi^1 done
    if (s < KSTAGES - 1) gen(s + 1);           // fill buf bi^1 while MFMA runs on buf bi
    #pragma unroll
    for (int ks = 0; ks < 2; ++ks) {
      const int cp = ((ks * 4 + kc) ^ ml7) * 8;
      bf16x8 af[4], bfr[4];
      #pragma unroll
      for (int mt = 0; mt < 4; ++mt)
        af[mt] = *(const bf16x8*)&As[bi][(wm * 64 + mt * 16 + ml) * 64 + cp];
      #pragma unroll
      for (int nt = 0; nt < 4; ++nt)
        bfr[nt] = *(const bf16x8*)&Bs[bi][(wn * 64 + nt * 16 + ml) * 64 + cp];
      #pragma unroll
      for (int mt = 0; mt < 4; ++mt)
        #pragma unroll
        for (int nt = 0; nt < 4; ++nt)
          acc[mt][nt] = __builtin_amdgcn_mfma_f32_16x16x32_bf16(af[mt], bfr[nt], acc[mt][nt], 0, 0, 0);
    }
  }

  // epilogue: C/D layout col=lane&15, row=quad*4+reg (m89/m91)
  const int quad = lane >> 4;
  const int obase = o0 + wn * 64 + ml;
  const size_t rbase = (size_t)(t0 + wm * 64 + quad * 4) * 1024;
  float bv[4];
  #pragma unroll
  for (int nt = 0; nt < 4; ++nt) bv[nt] = bias[obase + nt * 16];
  #pragma unroll
  for (int mt = 0; mt < 4; ++mt)
    #pragma unroll
    for (int r = 0; r < 4; ++r)
      #pragma unroll
      for (int nt = 0; nt < 4; ++nt)
        out[rbase + (size_t)(mt * 16 + r) * 1024 + obase + nt * 16] = acc[mt][nt][r] + bv[nt];
}

// ---- fallback (ws too small) — correct, slow, should never run
__global__ __launch_bounds__(256)
void cheby_naive(const float* __restrict__ x, const float* __restrict__ C,
                 float* __restrict__ out) {
  const int t = blockIdx.x, tid = threadIdx.x;
  float acc[4] = {0.f, 0.f, 0.f, 0.f};
  for (int i = 0; i < 1024; ++i) {
    float th = tanhf(x[(size_t)t * 1024 + i]);
    float T[9]; T[0] = 1.f; T[1] = th;
    #pragma unroll
    for (int d = 2; d < 9; ++d) T[d] = 2.f * th * T[d - 1] - T[d - 2];
    #pragma unroll
    for (int j = 0; j < 4; ++j) {
      const float* cp = &C[((size_t)i * 1024 + tid + j * 256) * 9];
      float s = 0.f;
      #pragma unroll
      for (int d = 0; d < 9; ++d) s += T[d] * cp[d];
      acc[j] += s;
    }
  }
  #pragma unroll
  for (int j = 0; j < 4; ++j) out[(size_t)t * 1024 + tid + j * 256] = acc[j];
}

extern "C" void kernel_launch(void* const* d_in, const int* in_sizes, int n_in,
                              void* d_out, int out_size, void* d_ws, size_t ws_size,
                              hipStream_t stream) {
  (void)in_sizes; (void)n_in; (void)out_size;
  const float* x = (const float*)d_in[0];
  const float* C = (const float*)d_in[1];
  float* out = (float*)d_out;

  const size_t bt_bytes = (size_t)1024 * KSTAGES * 64 * sizeof(bf16);  // 16.78 MB
  if (ws_size >= bt_bytes + 1024 * sizeof(float)) {
    bf16*  Bt   = (bf16*)d_ws;
    float* bias = (float*)((char*)d_ws + bt_bytes);
    hipMemsetAsync(bias, 0, 1024 * sizeof(float), stream);
    cheby_prep<<<dim3(32, 32), 256, 0, stream>>>(C, Bt, bias);
    cheby_gemm<<<256, 512, 0, stream>>>(x, Bt, bias, out);
  } else {
    cheby_naive<<<8192, 256, 0, stream>>>(x, C, out);
  }
}